// Round 13
// baseline (117.236 us; speedup 1.0000x reference)
//
#include <hip/hip_runtime.h>
#include <stdint.h>

// Problem constants: B=4, T=2048, C=512, H=8, D=64
typedef __attribute__((ext_vector_type(8))) __bf16 bf16x8;
typedef __attribute__((ext_vector_type(4))) __bf16 bf16x4;
typedef __attribute__((ext_vector_type(2))) __bf16 bf16x2;
typedef __attribute__((ext_vector_type(4))) float f32x4;
typedef __attribute__((ext_vector_type(16))) float f32x16;
typedef __attribute__((ext_vector_type(4))) unsigned u32x4;
typedef __attribute__((ext_vector_type(2))) int i32x2;

__device__ __forceinline__ unsigned short f2bf(float f) {
  unsigned u = __float_as_uint(f);
  u += 0x7FFFu + ((u >> 16) & 1u);   // round-to-nearest-even
  return (unsigned short)(u >> 16);
}

__device__ __forceinline__ float exp2fast(float x) {
#if __has_builtin(__builtin_amdgcn_exp2f)
  return __builtin_amdgcn_exp2f(x);
#else
  return __expf(x * 0.6931471805599453f);
#endif
}

__device__ __forceinline__ void pl32swap(unsigned &a, unsigned &b) {
#if __has_builtin(__builtin_amdgcn_permlane32_swap)
  i32x2 r = __builtin_amdgcn_permlane32_swap((int)a, (int)b, false, false);
  a = (unsigned)r[0]; b = (unsigned)r[1];
#else
  asm volatile("v_permlane32_swap_b32 %0, %1" : "+v"(a), "+v"(b));
#endif
}

// rows r, r+8, r+16, r+24 get distinct octets (2-way max aliasing anywhere);
// swz8(r+32) == swz8(r)   [used by the GEMM LDS staging only]
__device__ __forceinline__ int swz8(int r) { return (r & 7) ^ ((r >> 3) & 3); }

__device__ __forceinline__ void gload16(const unsigned short* src, unsigned short* ldsdst) {
  __builtin_amdgcn_global_load_lds(
      (const __attribute__((address_space(1))) unsigned int*)src,
      (__attribute__((address_space(3))) unsigned int*)ldsdst, 16, 0, 0);
}

// Stage 8 rows x 64 bf16 (128B/row) into LDS tile (linear dest), with the
// global-source octet XOR-swizzled by swz8(row) so swizzled reads are
// bank-conflict-free (G21: swizzle source+read, dest stays linear).
__device__ __forceinline__ void stage8(const unsigned short* gbase, long long strideElems,
                                       unsigned short* ldsTile, int rowBase) {
  const int lane = threadIdx.x & 63;
  const int r = rowBase + (lane >> 3);
  const int oct = (lane & 7) ^ swz8(r);
  gload16(gbase + (long long)r * strideElems + oct * 8, ldsTile + rowBase * 64);
}

// ---------------- merged prep kernel ----------------

__global__ __launch_bounds__(256) void prep(const float* __restrict__ x,
                                            unsigned short* __restrict__ xb,
                                            const float* __restrict__ wq,
                                            unsigned short* __restrict__ wqt,
                                            const float* __restrict__ wp,
                                            unsigned short* __restrict__ wpt,
                                            const int* __restrict__ adj,
                                            unsigned long long* __restrict__ mb) {
  int blk = blockIdx.x;
  if (blk < 16384) {
    int tid = blk * 256 + threadIdx.x;
    int4 v = ((const int4*)adj)[tid];
    unsigned n = (v.x != 0 ? 1u : 0u) | (v.y != 0 ? 2u : 0u) |
                 (v.z != 0 ? 4u : 0u) | (v.w != 0 ? 8u : 0u);
    unsigned long long part = (unsigned long long)n << ((threadIdx.x & 15) * 4);
    part |= __shfl_xor(part, 1);
    part |= __shfl_xor(part, 2);
    part |= __shfl_xor(part, 4);
    part |= __shfl_xor(part, 8);
    if ((threadIdx.x & 15) == 0) mb[tid >> 4] = part;
    return;
  }
  blk -= 16384;
  if (blk < 4096) {
    int i = (blk * 256 + threadIdx.x) * 4;
    float4 v = *(const float4*)(x + i);
    ushort4 o;
    o.x = f2bf(v.x); o.y = f2bf(v.y); o.z = f2bf(v.z); o.w = f2bf(v.w);
    *(ushort4*)(xb + i) = o;
    return;
  }
  blk -= 4096;
  const float* w; unsigned short* wt; int N; int bx, by;
  if (blk < 768) { w = wq; wt = wqt; N = 1536; bx = blk & 15; by = blk >> 4; }
  else { blk -= 768; w = wp; wt = wpt; N = 512; bx = blk & 15; by = blk >> 4; }
  __shared__ float tile[32][33];
  int k0 = bx * 32, n0 = by * 32;
  int tx = threadIdx.x & 31, ty = threadIdx.x >> 5;
#pragma unroll
  for (int i = 0; i < 4; i++)
    tile[ty + i * 8][tx] = w[(long long)(k0 + ty + i * 8) * N + n0 + tx];
  __syncthreads();
#pragma unroll
  for (int i = 0; i < 4; i++)
    wt[(long long)(n0 + ty + i * 8) * 512 + k0 + tx] = f2bf(tile[tx][ty + i * 8]);
}

// ---------------- GEMM core: C[128x128] = A[M,512] * Wt[N,512]^T ----------------
// m97 structure: single-buffered 32KB LDS, per K-step:
// barrier; stage; vmcnt(0); barrier; compute.

__device__ __forceinline__ void gemm_core(const unsigned short* __restrict__ A,
                                          const unsigned short* __restrict__ Wt,
                                          unsigned short* Al, unsigned short* Bl,
                                          int m0, int n0, f32x4 acc[4][4]) {
  const int lane = threadIdx.x & 63;
  const int wid = threadIdx.x >> 6;
  const int c = lane & 15, g = lane >> 4;
  const int wm = wid >> 1, wn = wid & 1;
  const unsigned short* Ab = A + (long long)m0 * 512;
  const unsigned short* Bb = Wt + (long long)n0 * 512;

  for (int k0 = 0; k0 < 512; k0 += 64) {
    __syncthreads();
#pragma unroll
    for (int i = 0; i < 4; i++) stage8(Ab + k0, 512, Al, wid * 32 + i * 8);
#pragma unroll
    for (int i = 0; i < 4; i++) stage8(Bb + k0, 512, Bl, wid * 32 + i * 8);
    asm volatile("s_waitcnt vmcnt(0)" ::: "memory");
    __syncthreads();
#pragma unroll
    for (int kk = 0; kk < 2; kk++) {
      bf16x8 af[4], bfr[4];
#pragma unroll
      for (int mi = 0; mi < 4; mi++) {
        int row = wm * 64 + mi * 16 + c;
        af[mi] = *(const bf16x8*)&Al[row * 64 + (((kk << 2) | g) ^ swz8(row)) * 8];
      }
#pragma unroll
      for (int ni = 0; ni < 4; ni++) {
        int row = wn * 64 + ni * 16 + c;
        bfr[ni] = *(const bf16x8*)&Bl[row * 64 + (((kk << 2) | g) ^ swz8(row)) * 8];
      }
#pragma unroll
      for (int mi = 0; mi < 4; mi++)
#pragma unroll
        for (int ni = 0; ni < 4; ni++)
          acc[mi][ni] = __builtin_amdgcn_mfma_f32_16x16x32_bf16(af[mi], bfr[ni], acc[mi][ni], 0, 0, 0);
    }
  }
}

// QKV GEMM. Outputs:
//  - qb: [bh][t][d] bf16, pre-scaled by 0.125*log2e
//  - kfb: K in MFMA A-fragment order: frag idx ((bh*32+t)*2+s)*4+cc holds, at
//    lane ln (16B): K[t*64 + s*32 + (ln&31)][(cc*2+(ln>>5))*8 .. +8]
//  - vfb: V^T in A-fragment order: same frag idx holds, at lane ln:
//    V[t*64 + (cc*2+(ln>>5))*8 .. +8][s*32 + (ln&31)]
// attn then loads every MFMA operand as ONE coalesced 1KB dwordx4 (no LDS).
__global__ __launch_bounds__(256) void gemm_qkv(const unsigned short* __restrict__ xb,
                                                const unsigned short* __restrict__ wqt,
                                                const float* __restrict__ bqkv,
                                                unsigned short* __restrict__ qb,
                                                unsigned short* __restrict__ kfb,
                                                unsigned short* __restrict__ vfb) {
  __shared__ __align__(16) unsigned short Al[128 * 64];
  __shared__ __align__(16) unsigned short Bl[128 * 64];
  f32x4 acc[4][4] = {};
  int m0 = blockIdx.x * 128, n0 = blockIdx.y * 128;
  gemm_core(xb, wqt, Al, Bl, m0, n0, acc);
  const int lane = threadIdx.x & 63;
  const int wid = threadIdx.x >> 6;
  const int c = lane & 15, g = lane >> 4;
  const int wm = wid >> 1, wn = wid & 1;
#pragma unroll
  for (int ni = 0; ni < 4; ni++) {
    int n = n0 + wn * 64 + ni * 16 + c;
    float bv = bqkv[n];
    int which = n >> 9;
    int h = (n & 511) >> 6, d = n & 63;
#pragma unroll
    for (int mi = 0; mi < 4; mi++) {
      int mbase = m0 + wm * 64 + mi * 16 + g * 4;   // 4 consecutive tokens, same batch
      int b = mbase >> 11, t0 = mbase & 2047;
      int bh = b * 8 + h;
      if (which == 2) {
        // VF: 4 consecutive kv land in one fragment -> one 8B store
        int t = t0 >> 6, wv = t0 & 63, f = wv >> 3;
        int cc = f >> 1, h5p = f & 1, s = d >> 5;
        int ln = h5p * 32 + (d & 31), el = t0 & 7;
        long long fi = (((long long)bh * 32 + t) * 2 + s) * 4 + cc;
        ushort4 o;
        o.x = f2bf(acc[mi][ni][0] + bv); o.y = f2bf(acc[mi][ni][1] + bv);
        o.z = f2bf(acc[mi][ni][2] + bv); o.w = f2bf(acc[mi][ni][3] + bv);
        *(ushort4*)&vfb[(fi * 64 + ln) * 8 + el] = o;
      } else if (which == 0) {
#pragma unroll
        for (int j = 0; j < 4; j++)
          qb[(bh * 2048 + t0 + j) * 64 + d] = f2bf((acc[mi][ni][j] + bv) * 0.18033688011112042f);
      } else {
        // KF: 4 consecutive tokens -> same fragment, lane stride 1 (16B apart)
        int cc = d >> 4, h5p = (d >> 3) & 1, el = d & 7;
        int t = t0 >> 6, s = (t0 >> 5) & 1;
        long long fi = (((long long)bh * 32 + t) * 2 + s) * 4 + cc;
        long long base = (fi * 64 + (h5p * 32 + (t0 & 31))) * 8 + el;
#pragma unroll
        for (int j = 0; j < 4; j++)
          kfb[base + j * 8] = f2bf(acc[mi][ni][j] + bv);
      }
    }
  }
}

__global__ __launch_bounds__(256) void gemm_proj(const unsigned short* __restrict__ yb,
                                                 const unsigned short* __restrict__ wpt,
                                                 const float* __restrict__ bproj,
                                                 float* __restrict__ out) {
  __shared__ __align__(16) unsigned short Al[128 * 64];
  __shared__ __align__(16) unsigned short Bl[128 * 64];
  f32x4 acc[4][4] = {};
  int m0 = blockIdx.x * 128, n0 = blockIdx.y * 128;
  gemm_core(yb, wpt, Al, Bl, m0, n0, acc);
  const int lane = threadIdx.x & 63;
  const int wid = threadIdx.x >> 6;
  const int c = lane & 15, g = lane >> 4;
  const int wm = wid >> 1, wn = wid & 1;
#pragma unroll
  for (int ni = 0; ni < 4; ni++) {
    int n = n0 + wn * 64 + ni * 16 + c;
    float bv = bproj[n];
#pragma unroll
    for (int mi = 0; mi < 4; mi++) {
      int mbase = m0 + wm * 64 + mi * 16 + g * 4;
#pragma unroll
      for (int j = 0; j < 4; j++)
        out[(long long)(mbase + j) * 512 + n] = acc[mi][ni][j] + bv;
    }
  }
}

// ---------------- flash attention: fragment-direct, barrier-free ----------------
// Grid 2048 x 128 thr. bh = bid&31 (XCD-colocated), qblk = bid>>5 (32 q-rows).
// 2 waves per block = the 2 kv halves of the SAME 32 q-rows; each wave streams
// its half fully independently: every MFMA operand is one coalesced 1KB
// global_load_dwordx4 from the pre-arranged KF/VF fragment buffers (L2-served;
// ~3.5MB working set per XCD). No K/V LDS, no per-tile barriers, no swizzle —
// the round-7..12 lockstep convoy is gone. 8 blocks/CU -> 16 waves/CU.
// No-max exp2 softmax => halves add exactly; one LDS combine at block end.
__global__ __launch_bounds__(128, 4) void attn(const unsigned short* __restrict__ qb,
                                               const unsigned short* __restrict__ kfb,
                                               const unsigned short* __restrict__ vfb,
                                               const unsigned long long* __restrict__ mbits,
                                               unsigned short* __restrict__ yb) {
  __shared__ __align__(16) float lut4[16][4];   // nibble -> f32x4 seed (0 / -1e30)
  __shared__ __align__(16) float xch[64][36];   // wave-1 O-partial donation
  __shared__ float xl[64];                      // wave-1 l-partial donation
  const int lane = threadIdx.x & 63;
  const int w = threadIdx.x >> 6;               // wave = kv half
  const int l31 = lane & 31, h5 = lane >> 5;
  const int bid = blockIdx.x;
  const int bh = bid & 31;                      // xcd = bid%8 = bh%8
  const int q0 = (bid >> 5) * 32;
  const int b = bh >> 3, h = bh & 7;
  const int qglob = q0 + l31;

  if (threadIdx.x < 16) {
    int n = threadIdx.x;
#pragma unroll
    for (int j = 0; j < 4; j++) lut4[n][j] = ((n >> j) & 1) ? 0.0f : -1e30f;
  }
  __syncthreads();

  const unsigned short* qptr = qb + ((long long)bh * 2048 + qglob) * 64;
  bf16x8 qf[4];
#pragma unroll
  for (int cc = 0; cc < 4; cc++) qf[cc] = *(const bf16x8*)(qptr + cc * 16 + h5 * 8);

  const unsigned long long* mrow = mbits + ((long long)b * 2048 + qglob) * 32 + w * 16;

  // fragment pointers for this kv half; per-tile stride = 8 frags = 4096 elems
  const unsigned short* kfp = kfb + ((long long)(bh * 32 + w * 16) * 8) * 512 + lane * 8;
  const unsigned short* vfp = vfb + ((long long)(bh * 32 + w * 16) * 8) * 512 + lane * 8;

  f32x16 accO0 = {0,0,0,0, 0,0,0,0, 0,0,0,0, 0,0,0,0};
  f32x16 accO1 = {0,0,0,0, 0,0,0,0, 0,0,0,0, 0,0,0,0};
  float lsum = 0.0f;

  for (int t = 0; t < 16; ++t) {
    // ---- K fragments: 8 coalesced 1KB loads ----
    bf16x8 kf0[4], kf1[4];
#pragma unroll
    for (int cc = 0; cc < 4; cc++) {
      kf0[cc] = *(const bf16x8*)(kfp + cc * 512);          // s=0: kv rows 0..31
      kf1[cc] = *(const bf16x8*)(kfp + 2048 + cc * 512);   // s=1: kv rows 32..63
    }
    unsigned long long mw = mrow[t];

    // ---- seed S^T accumulators from the nibble LUT ----
    // C reg r of tile ot: kv = ot*32 + (r&3) + 8*(r>>2) + 4*h5
    unsigned lo = (unsigned)mw, hi = (unsigned)(mw >> 32);
    f32x16 st0, st1;
#pragma unroll
    for (int j = 0; j < 4; j++) {
      f32x4 s0 = *(const f32x4*)lut4[(lo >> (8 * j + 4 * h5)) & 0xF];
      f32x4 s1 = *(const f32x4*)lut4[(hi >> (8 * j + 4 * h5)) & 0xF];
#pragma unroll
      for (int i = 0; i < 4; i++) { st0[4 * j + i] = s0[i]; st1[4 * j + i] = s1[i]; }
    }

    // ---- S^T = K * Q^T ----
    __builtin_amdgcn_s_setprio(1);
#pragma unroll
    for (int cc = 0; cc < 4; cc++) {
      st0 = __builtin_amdgcn_mfma_f32_32x32x16_bf16(kf0[cc], qf[cc], st0, 0, 0, 0);
      st1 = __builtin_amdgcn_mfma_f32_32x32x16_bf16(kf1[cc], qf[cc], st1, 0, 0, 0);
    }
    __builtin_amdgcn_s_setprio(0);

    // ---- V fragments issued now; latency hides under exp2 ----
    bf16x8 vf0[4], vf1[4];
#pragma unroll
    for (int cc = 0; cc < 4; cc++) {
      vf0[cc] = *(const bf16x8*)(vfp + cc * 512);          // s=0: d 0..31
      vf1[cc] = *(const bf16x8*)(vfp + 2048 + cc * 512);   // s=1: d 32..63
    }

    // ---- exp2 softmax (masked entries hit exp2(-1e30) = 0), pack bf16 ----
    unsigned pd[2][8];
#pragma unroll
    for (int m = 0; m < 8; m++) {
      float p0 = exp2fast(st0[2 * m]);
      float p1 = exp2fast(st0[2 * m + 1]);
      float p2 = exp2fast(st1[2 * m]);
      float p3 = exp2fast(st1[2 * m + 1]);
      lsum += (p0 + p1) + (p2 + p3);
      bf16x2 v0 = {(__bf16)p0, (__bf16)p1};
      bf16x2 v1 = {(__bf16)p2, (__bf16)p3};
      pd[0][m] = __builtin_bit_cast(unsigned, v0);
      pd[1][m] = __builtin_bit_cast(unsigned, v1);
    }

    // ---- PV B-fragments: l <-> l+32 dword exchange ----
#pragma unroll
    for (int ot = 0; ot < 2; ot++)
#pragma unroll
      for (int hc = 0; hc < 2; hc++) {
        pl32swap(pd[ot][4 * hc + 0], pd[ot][4 * hc + 2]);
        pl32swap(pd[ot][4 * hc + 1], pd[ot][4 * hc + 3]);
      }

    // ---- O^T += V^T * P^T ----
    __builtin_amdgcn_s_setprio(1);
#pragma unroll
    for (int cc = 0; cc < 4; cc++) {
      u32x4 pu = {pd[cc >> 1][4 * (cc & 1) + 0], pd[cc >> 1][4 * (cc & 1) + 1],
                  pd[cc >> 1][4 * (cc & 1) + 2], pd[cc >> 1][4 * (cc & 1) + 3]};
      bf16x8 pf = __builtin_bit_cast(bf16x8, pu);
      accO0 = __builtin_amdgcn_mfma_f32_32x32x16_bf16(vf0[cc], pf, accO0, 0, 0, 0);
      accO1 = __builtin_amdgcn_mfma_f32_32x32x16_bf16(vf1[cc], pf, accO1, 0, 0, 0);
    }
    __builtin_amdgcn_s_setprio(0);

    kfp += 4096;
    vfp += 4096;
  }

  // full row-sum for this half (lane's lsum covers its h5 kv-subset)
  float lh = lsum + __shfl_xor(lsum, 32);

  // ---- cross-half combine: wave 1 donates, wave 0 writes y ----
  if (w == 1) {
    float* dst = &xch[lane][0];
#pragma unroll
    for (int m = 0; m < 4; m++) {
      *(f32x4*)(dst + 4 * m) = f32x4{accO0[4 * m + 0], accO0[4 * m + 1],
                                     accO0[4 * m + 2], accO0[4 * m + 3]};
      *(f32x4*)(dst + 16 + 4 * m) = f32x4{accO1[4 * m + 0], accO1[4 * m + 1],
                                          accO1[4 * m + 2], accO1[4 * m + 3]};
    }
    xl[lane] = lh;
  }
  __syncthreads();
  if (w == 0) {
    const float* src = &xch[lane][0];
    float linv = 1.0f / (lh + xl[lane]);
    unsigned short* yrow = yb + ((long long)(b * 2048 + qglob)) * 512 + h * 64;
#pragma unroll
    for (int m = 0; m < 4; m++) {
      f32x4 a = *(const f32x4*)(src + 4 * m);
      f32x4 c = *(const f32x4*)(src + 16 + 4 * m);
      int d0 = 8 * m + 4 * h5;
      bf16x4 o0 = {(__bf16)((accO0[4 * m + 0] + a[0]) * linv),
                   (__bf16)((accO0[4 * m + 1] + a[1]) * linv),
                   (__bf16)((accO0[4 * m + 2] + a[2]) * linv),
                   (__bf16)((accO0[4 * m + 3] + a[3]) * linv)};
      bf16x4 o1 = {(__bf16)((accO1[4 * m + 0] + c[0]) * linv),
                   (__bf16)((accO1[4 * m + 1] + c[1]) * linv),
                   (__bf16)((accO1[4 * m + 2] + c[2]) * linv),
                   (__bf16)((accO1[4 * m + 3] + c[3]) * linv)};
      *(bf16x4*)&yrow[d0] = o0;
      *(bf16x4*)&yrow[32 + d0] = o1;
    }
  }
}

// ---------------- launcher ----------------

extern "C" void kernel_launch(void* const* d_in, const int* in_sizes, int n_in,
                              void* d_out, int out_size, void* d_ws, size_t ws_size,
                              hipStream_t stream) {
  const float* x      = (const float*)d_in[0];
  const int*   adj    = (const int*)d_in[1];
  const float* w_qkv  = (const float*)d_in[2];
  const float* b_qkv  = (const float*)d_in[3];
  const float* w_proj = (const float*)d_in[4];
  const float* b_proj = (const float*)d_in[5];
  float* out = (float*)d_out;

  char* ws = (char*)d_ws;
  unsigned short* xb  = (unsigned short*)(ws);              // 8.4MB  (reused as yb)
  unsigned short* qb  = (unsigned short*)(ws + 8388608);    // 8.4MB
  unsigned short* kfb = (unsigned short*)(ws + 16777216);   // 8.4MB  K fragments
  unsigned short* vfb = (unsigned short*)(ws + 25165824);   // 8.4MB  V fragments
  unsigned short* wqt = (unsigned short*)(ws + 33554432);   // 1.57MB
  unsigned short* wpt = (unsigned short*)(ws + 35127296);   // 0.52MB
  unsigned long long* mb = (unsigned long long*)(ws + 35651584); // 2MB  (end 37.75MB)
  unsigned short* yb = xb;  // x is dead after gemm_qkv

  prep<<<dim3(21504), dim3(256), 0, stream>>>(x, xb, w_qkv, wqt, w_proj, wpt, adj, mb);
  gemm_qkv<<<dim3(64, 12), dim3(256), 0, stream>>>(xb, wqt, b_qkv, qb, kfb, vfb);
  attn<<<dim3(2048), dim3(128), 0, stream>>>(qb, kfb, vfb, mb, yb);
  gemm_proj<<<dim3(64, 4), dim3(256), 0, stream>>>(yb, wpt, b_proj, out);
}